// Round 4
// baseline (2379.809 us; speedup 1.0000x reference)
//
#include <hip/hip_runtime.h>
#include <math.h>

// Problem constants: B=8, CIN=3, COUT=16, H=W=384
#define BQ   8
#define CIN  3
#define COUT 16
#define HW   (384 * 384)            // 147456
#define NPIX (BQ * HW)              // 1,179,648 pixels
#define NELT 18874368.0f            // NPIX * COUT
#define MAX_ITERS 16

#define TPB       256
#define BPC       6                 // 6 blocks/CU: streamed state needs ~50 VGPR -> fits 85 budget
#define NBLK      (BPC * 256)       // 1536 blocks, co-resident (LDS 512B, VGPR<=85, 24 waves/CU)
#define NTHREADS  (NBLK * TPB)      // 393,216
#define PPT       3                 // 393,216 * 3 == NPIX exactly

#define NLEAF        64
#define BLK_PER_LEAF (NBLK / NLEAF) // 24

struct __align__(64) PadCnt { int cnt; int pad[15]; };  // one cache line each

struct Ctl {
    PadCnt leaf[NLEAF];                 // barrier leaf counters (24-way fan-in)
    PadCnt root;                        // barrier root counter (64-way fan-in)
    PadCnt sense;                       // barrier sense (read-only spin target)
    float  partials[2][NBLK];           // ping-pong per-block |v| partial sums
};

__global__ void k_init(Ctl* c) {
    int t = threadIdx.x;
    if (t < NLEAF) c->leaf[t].cnt = 0;
    if (t == 0) { c->root.cnt = 0; c->sense.cnt = 0; }
}

// tanh(x) = 1 - 2/(exp(2x)+1): v_exp_f32 + v_rcp_f32, ~6 instrs, ~1e-7 abs err.
__device__ __forceinline__ float tanh_fast(float x) {
    float e = __expf(2.0f * x);
    return fmaf(-2.0f, __builtin_amdgcn_rcpf(e + 1.0f), 1.0f);
}

// block = 256 threads = 4 waves; full block sum returned on tid 0
__device__ __forceinline__ float block_reduce_add(float v) {
    #pragma unroll
    for (int off = 32; off > 0; off >>= 1)
        v += __shfl_down(v, off, 64);
    __shared__ float red[TPB / 64];
    int lane = threadIdx.x & 63;
    int wid  = threadIdx.x >> 6;
    if (lane == 0) red[wid] = v;
    __syncthreads();
    float r = 0.f;
    if (threadIdx.x == 0) {
        #pragma unroll
        for (int i = 0; i < TPB / 64; ++i) r += red[i];
    }
    return r;
}

// Two-level sense-reversing grid barrier: leaf fan-in 24, root fan-in 64.
// The agent-scope ACQ_REL atomics double as release/acquire fences
// (buffer_wbl2 / buffer_inv), making the streamed state written before the
// barrier visible to all XCDs after it.
__device__ __forceinline__ void grid_barrier(Ctl* c, int* sense_sh) {
    __syncthreads();
    if (threadIdx.x == 0) {
        int next = *sense_sh ^ 1;
        int lf = blockIdx.x & (NLEAF - 1);
        int p = __hip_atomic_fetch_add(&c->leaf[lf].cnt, 1, __ATOMIC_ACQ_REL,
                                       __HIP_MEMORY_SCOPE_AGENT);
        if (p == BLK_PER_LEAF - 1) {
            __hip_atomic_store(&c->leaf[lf].cnt, 0, __ATOMIC_RELAXED,
                               __HIP_MEMORY_SCOPE_AGENT);
            int q = __hip_atomic_fetch_add(&c->root.cnt, 1, __ATOMIC_ACQ_REL,
                                           __HIP_MEMORY_SCOPE_AGENT);
            if (q == NLEAF - 1) {
                __hip_atomic_store(&c->root.cnt, 0, __ATOMIC_RELAXED,
                                   __HIP_MEMORY_SCOPE_AGENT);
                __hip_atomic_store(&c->sense.cnt, next, __ATOMIC_RELEASE,
                                   __HIP_MEMORY_SCOPE_AGENT);
            }
        }
        while (__hip_atomic_load(&c->sense.cnt, __ATOMIC_ACQUIRE,
                                 __HIP_MEMORY_SCOPE_AGENT) != next)
            __builtin_amdgcn_s_sleep(4);
        *sense_sh = next;
    }
    __syncthreads();
}

// Deterministic grid sum: wave 0 sums all NBLK partials in a fixed order
// (identical in every block -> bitwise-identical -> uniform decision).
__device__ __forceinline__ float grid_sum(const float* part, float* bc) {
    int lane = threadIdx.x & 63, wid = threadIdx.x >> 6;
    if (wid == 0) {
        float s = 0.f;
        #pragma unroll
        for (int i = 0; i < NBLK / 64; ++i)
            s += __hip_atomic_load(&part[i * 64 + lane], __ATOMIC_RELAXED,
                                   __HIP_MEMORY_SCOPE_AGENT);
        #pragma unroll
        for (int off = 32; off > 0; off >>= 1)
            s += __shfl_down(s, off, 64);
        if (lane == 0) *bc = s;
    }
    __syncthreads();
    return *bc;
}

// ---- streamed-state phases. State lives IN `out` ([b][o][hw] layout), updated
// in place: 1x1 conv => each pixel's 16 channels owned by exactly one thread.

#define PRE_PIXEL(kk)                                                    \
    { int p = tid + (kk) * NTHREADS; int b = p / HW; int hw = p - b * HW;\
      const float* xb = x + (size_t)b * (CIN * HW) + hw;                 \
      float* vb = out + (size_t)b * (COUT * HW) + hw;                    \
      float x0 = xb[0], x1 = xb[HW], x2 = xb[2 * HW];                    \
      _Pragma("unroll")                                                  \
      for (int o = 0; o < COUT; ++o) {                                   \
          float a = bp[o];                                               \
          a = fmaf(wp[o * CIN + 0], x0, a);                              \
          a = fmaf(wp[o * CIN + 1], x1, a);                              \
          a = fmaf(wp[o * CIN + 2], x2, a);                              \
          vb[(size_t)o * HW] = a; s += fabsf(a);                         \
      } }

#define ITER_PIXEL(kk)                                                   \
    { int p = tid + (kk) * NTHREADS; int b = p / HW; int hw = p - b * HW;\
      float* vb = out + (size_t)b * (COUT * HW) + hw;                    \
      float v[COUT], u[COUT];                                            \
      _Pragma("unroll")                                                  \
      for (int c = 0; c < COUT; ++c) v[c] = vb[(size_t)c * HW];          \
      _Pragma("unroll")                                                  \
      for (int o = 0; o < COUT; ++o) {                                   \
          float a = bs[o];                                               \
          _Pragma("unroll")                                              \
          for (int c = 0; c < COUT; ++c)                                 \
              a = fmaf(ws[o * COUT + c], v[c], a);                       \
          u[o] = tanh_fast(a);                                           \
      }                                                                  \
      _Pragma("unroll")                                                  \
      for (int o = 0; o < COUT; ++o) {                                   \
          float a = bl[o];                                               \
          _Pragma("unroll")                                              \
          for (int c = 0; c < COUT; ++c)                                 \
              a = fmaf(wl[o * COUT + c], u[c], a);                       \
          a *= 10.f;                                                     \
          vb[(size_t)o * HW] = a; s += fabsf(a);                         \
      } }

#define FIN_PIXEL(kk)                                                    \
    { int p = tid + (kk) * NTHREADS; int b = p / HW; int hw = p - b * HW;\
      float* vb = out + (size_t)b * (COUT * HW) + hw;                    \
      float v[COUT];                                                     \
      _Pragma("unroll")                                                  \
      for (int c = 0; c < COUT; ++c) v[c] = vb[(size_t)c * HW];          \
      _Pragma("unroll")                                                  \
      for (int o = 0; o < COUT; ++o) {                                   \
          float a = bs[o];                                               \
          _Pragma("unroll")                                              \
          for (int c = 0; c < COUT; ++c)                                 \
              a = fmaf(ws[o * COUT + c], v[c], a);                       \
          vb[(size_t)o * HW] = a;                                        \
      } }

__global__ __launch_bounds__(TPB, BPC) void k_persist(
        const float* __restrict__ x,
        const float* __restrict__ wp, const float* __restrict__ bp,
        const float* __restrict__ wl, const float* __restrict__ bl,
        const float* __restrict__ ws, const float* __restrict__ bs,
        float* __restrict__ out, Ctl* __restrict__ ctl) {
    __shared__ int sense_sh;
    __shared__ float bcast;
    const int t = threadIdx.x;
    if (t == 0) sense_sh = 0;
    __syncthreads();

    const int tid = blockIdx.x * TPB + t;

    // ---- pre conv + |v| partial (state -> out)
    float s = 0.f;
    PRE_PIXEL(0) PRE_PIXEL(1) PRE_PIXEL(2)
    {
        float r = block_reduce_add(s);
        if (t == 0)
            __hip_atomic_store(&ctl->partials[0][blockIdx.x], r,
                               __ATOMIC_RELAXED, __HIP_MEMORY_SCOPE_AGENT);
    }
    grid_barrier(ctl, &sense_sh);

    // ---- while (mean|v| < 3): v = 10*(wl @ tanh(ws @ v + bs) + bl), in place
    int it = 0;
    while (it < MAX_ITERS) {
        float total = grid_sum(ctl->partials[it & 1], &bcast);
        if (total >= 3.0f * NELT) break;      // uniform across all blocks

        s = 0.f;
        ITER_PIXEL(0) ITER_PIXEL(1) ITER_PIXEL(2)
        ++it;
        float r = block_reduce_add(s);
        if (t == 0)
            __hip_atomic_store(&ctl->partials[it & 1][blockIdx.x], r,
                               __ATOMIC_RELAXED, __HIP_MEMORY_SCOPE_AGENT);
        grid_barrier(ctl, &sense_sh);
    }

    // ---- final conv, in place (read 16, compute, overwrite same 16)
    FIN_PIXEL(0) FIN_PIXEL(1) FIN_PIXEL(2)
}

extern "C" void kernel_launch(void* const* d_in, const int* in_sizes, int n_in,
                              void* d_out, int out_size, void* d_ws, size_t ws_size,
                              hipStream_t stream) {
    // dict order: x, w_pre, b_pre, w_loop, b_loop, w_shared, b_shared
    const float* x  = (const float*)d_in[0];
    const float* wp = (const float*)d_in[1];
    const float* bp = (const float*)d_in[2];
    const float* wl = (const float*)d_in[3];
    const float* bl = (const float*)d_in[4];
    const float* ws = (const float*)d_in[5];
    const float* bs = (const float*)d_in[6];
    float* out = (float*)d_out;
    Ctl*   ctl = (Ctl*)d_ws;

    k_init<<<1, 64, 0, stream>>>(ctl);
    k_persist<<<NBLK, TPB, 0, stream>>>(x, wp, bp, wl, bl, ws, bs, out, ctl);
}

// Round 6
// 514.743 us; speedup vs baseline: 4.6233x; 4.6233x over previous
//
#include <hip/hip_runtime.h>
#include <math.h>

// Problem constants: B=8, CIN=3, COUT=16, H=W=384
#define BQ   8
#define CIN  3
#define COUT 16
#define HW   (384 * 384)            // 147456
#define NPIX (BQ * HW)              // 1,179,648 pixels
#define NELT 18874368.0f            // NPIX * COUT
#define MAX_ITERS 16

#define TPB       256
#define BPC       2                 // 2 blocks/CU: the PROVEN zero-spill budget (256 reg/wave)
#define NBLK      (BPC * 256)       // 512 blocks, co-resident by construction
#define NTHREADS  (NBLK * TPB)      // 131,072
#define PPT       9                 // 131,072 * 9 == NPIX exactly; 144 state floats/thread

#define NLEAF        64
#define BLK_PER_LEAF (NBLK / NLEAF) // 8

#define SCOPE_AGENT __HIP_MEMORY_SCOPE_AGENT

typedef float vfloat16 __attribute__((ext_vector_type(16)));

// One cache line per node: arrival counter + float accumulator.
struct __align__(64) Node { int cnt; float acc; int pad[14]; };

struct Ctl {
    Node leaf[NLEAF];   // leaf fan-in 8: counts + partial-sum accumulation
    Node root;          // root fan-in 64
    Node sense;         // .cnt = monotonically increasing (round<<1 | stop)
};

__global__ void k_init(Ctl* c) {
    int t = threadIdx.x;
    if (t < NLEAF) { c->leaf[t].cnt = 0; c->leaf[t].acc = 0.f; }
    if (t == 0) {
        c->root.cnt = 0; c->root.acc = 0.f;
        c->sense.cnt = 0; c->sense.acc = 0.f;
    }
}

// tanh(x) = 1 - 2/(exp(2x)+1): v_exp_f32 + v_rcp_f32, ~6 instrs, ~1e-7 abs err.
__device__ __forceinline__ float tanh_fast(float x) {
    float e = __expf(2.0f * x);
    return fmaf(-2.0f, __builtin_amdgcn_rcpf(e + 1.0f), 1.0f);
}

// Completion fence at the LLC coherence point WITHOUT cache maintenance:
// all cross-block ops here are agent-scope atomics (execute at the LLC), so
// draining vmcnt orders them without buffer_wbl2 / buffer_inv.
__device__ __forceinline__ void vm_drain() {
    asm volatile("s_waitcnt vmcnt(0)" ::: "memory");
}

// block = 256 threads = 4 waves; full block sum returned on tid 0
__device__ __forceinline__ float block_reduce_add(float v) {
    #pragma unroll
    for (int off = 32; off > 0; off >>= 1)
        v += __shfl_down(v, off, 64);
    __shared__ float red[TPB / 64];
    int lane = threadIdx.x & 63;
    int wid  = threadIdx.x >> 6;
    if (lane == 0) red[wid] = v;
    __syncthreads();
    float r = 0.f;
    if (threadIdx.x == 0) {
        #pragma unroll
        for (int i = 0; i < TPB / 64; ++i) r += red[i];
    }
    return r;
}

// Fused reduction + barrier + uniform decision, coherence-maintenance-free.
// All cross-block traffic = relaxed agent-scope atomic RMWs (LLC-coherent by
// construction; no wbl2/inv storms). The root-last thread alone evaluates the
// stop condition and publishes (round<<1 | stop) in a monotonic sense word.
// LIVENESS: the spin uses an atomic RMW (fetch_add 0) every 8th poll — RMWs
// always execute at the LLC, so a fresh value is guaranteed regardless of any
// stale lines in the local XCD L2. No reliance on acquire lowering.
__device__ __forceinline__ int arrive_and_decide(Ctl* c, float v, int round,
                                                 int* stop_sh) {
    float r = block_reduce_add(v);
    if (threadIdx.x == 0) {
        int lf = blockIdx.x & (NLEAF - 1);
        // 1) merge this block's partial into the leaf accumulator (at LLC)
        __hip_atomic_fetch_add(&c->leaf[lf].acc, r, __ATOMIC_RELAXED, SCOPE_AGENT);
        vm_drain();                                   // acc landed before cnt
        int p = __hip_atomic_fetch_add(&c->leaf[lf].cnt, 1, __ATOMIC_RELAXED,
                                       SCOPE_AGENT);
        if (p == BLK_PER_LEAF - 1) {
            // leaf complete: drain acc (exchange reads+resets), reset cnt
            float sl = __hip_atomic_exchange(&c->leaf[lf].acc, 0.0f,
                                             __ATOMIC_RELAXED, SCOPE_AGENT);
            __hip_atomic_exchange(&c->leaf[lf].cnt, 0, __ATOMIC_RELAXED,
                                  SCOPE_AGENT);
            vm_drain();                               // resets done before root
            __hip_atomic_fetch_add(&c->root.acc, sl, __ATOMIC_RELAXED,
                                   SCOPE_AGENT);
            vm_drain();
            int q = __hip_atomic_fetch_add(&c->root.cnt, 1, __ATOMIC_RELAXED,
                                           SCOPE_AGENT);
            if (q == NLEAF - 1) {
                float total = __hip_atomic_exchange(&c->root.acc, 0.0f,
                                                    __ATOMIC_RELAXED, SCOPE_AGENT);
                __hip_atomic_exchange(&c->root.cnt, 0, __ATOMIC_RELAXED,
                                      SCOPE_AGENT);
                vm_drain();                           // resets done before publish
                int stop = (total >= 3.0f * NELT) ? 1 : 0;
                __hip_atomic_exchange(&c->sense.cnt, (round << 1) | stop,
                                      __ATOMIC_RELAXED, SCOPE_AGENT);
            }
        }
        // spin: cheap relaxed loads, RMW every 8th poll (guaranteed-fresh).
        int s, polls = 0;
        for (;;) {
            if ((polls & 7) == 0)
                s = __hip_atomic_fetch_add(&c->sense.cnt, 0, __ATOMIC_RELAXED,
                                           SCOPE_AGENT);
            else
                s = __hip_atomic_load(&c->sense.cnt, __ATOMIC_RELAXED,
                                      SCOPE_AGENT);
            if ((s >> 1) >= round) break;
            ++polls;
            __builtin_amdgcn_s_sleep(8);
        }
        *stop_sh = s & 1;
    }
    __syncthreads();
    return *stop_sh;
}

// ---- per-pixel macros over NAMED ext-vectors (no arrays -> guaranteed SROA) ----

#define PRE_PIXEL(vk, kk)                                                \
    { int p = tid + (kk) * NTHREADS; int b = p / HW; int hw = p - b * HW;\
      const float* xb = x + (size_t)b * (CIN * HW) + hw;                 \
      float x0 = xb[0], x1 = xb[HW], x2 = xb[2 * HW];                    \
      _Pragma("unroll")                                                  \
      for (int o = 0; o < COUT; ++o) {                                   \
          float a = bp[o];                                               \
          a = fmaf(wp[o * CIN + 0], x0, a);                              \
          a = fmaf(wp[o * CIN + 1], x1, a);                              \
          a = fmaf(wp[o * CIN + 2], x2, a);                              \
          vk[o] = a; s += fabsf(a);                                      \
      } }

#define STEP_PIXEL(vk)                                                   \
    { float tt[COUT];                                                    \
      _Pragma("unroll")                                                  \
      for (int o = 0; o < COUT; ++o) {                                   \
          float a = bs[o];                                               \
          _Pragma("unroll")                                              \
          for (int c = 0; c < COUT; ++c)                                 \
              a = fmaf(ws[o * COUT + c], vk[c], a);                      \
          tt[o] = tanh_fast(a);                                          \
      }                                                                  \
      _Pragma("unroll")                                                  \
      for (int o = 0; o < COUT; ++o) {                                   \
          float a = bl[o];                                               \
          _Pragma("unroll")                                              \
          for (int c = 0; c < COUT; ++c)                                 \
              a = fmaf(wl[o * COUT + c], tt[c], a);                      \
          a *= 10.f;                                                     \
          vk[o] = a; s += fabsf(a);                                      \
      } }

#define FIN_PIXEL(vk, kk)                                                \
    { int p = tid + (kk) * NTHREADS; int b = p / HW; int hw = p - b * HW;\
      float* ob = out + (size_t)b * (COUT * HW) + hw;                    \
      _Pragma("unroll")                                                  \
      for (int o = 0; o < COUT; ++o) {                                   \
          float a = bs[o];                                               \
          _Pragma("unroll")                                              \
          for (int c = 0; c < COUT; ++c)                                 \
              a = fmaf(ws[o * COUT + c], vk[c], a);                      \
          ob[(size_t)o * HW] = a;                                        \
      } }

__global__ __launch_bounds__(TPB, BPC) void k_persist(
        const float* __restrict__ x,
        const float* __restrict__ wp, const float* __restrict__ bp,
        const float* __restrict__ wl, const float* __restrict__ bl,
        const float* __restrict__ ws, const float* __restrict__ bs,
        float* __restrict__ out, Ctl* __restrict__ ctl) {
    __shared__ int stop_sh;
    const int t = threadIdx.x;
    const int tid = blockIdx.x * TPB + t;

    // State: 9 named 16-wide vectors = 144 registers. No runtime indexing.
    // Proven zero-spill at 2 blocks/CU (R0: FETCH 12.5 MB, WRITE 83 MB).
    vfloat16 v0, v1, v2, v3, v4, v5, v6, v7, v8;

    // ---- pre conv + |v| partial
    float s = 0.f;
    PRE_PIXEL(v0, 0) PRE_PIXEL(v1, 1) PRE_PIXEL(v2, 2)
    PRE_PIXEL(v3, 3) PRE_PIXEL(v4, 4) PRE_PIXEL(v5, 5)
    PRE_PIXEL(v6, 6) PRE_PIXEL(v7, 7) PRE_PIXEL(v8, 8)

    int round = 1;
    int stop = arrive_and_decide(ctl, s, round, &stop_sh);

    // ---- while (mean|v| < 3): v = 10*(wl @ tanh(ws @ v + bs) + bl)
    int it = 0;
    while (!stop && it < MAX_ITERS) {
        s = 0.f;
        STEP_PIXEL(v0) STEP_PIXEL(v1) STEP_PIXEL(v2)
        STEP_PIXEL(v3) STEP_PIXEL(v4) STEP_PIXEL(v5)
        STEP_PIXEL(v6) STEP_PIXEL(v7) STEP_PIXEL(v8)
        ++it; ++round;
        stop = arrive_and_decide(ctl, s, round, &stop_sh);
    }

    // ---- final conv
    FIN_PIXEL(v0, 0) FIN_PIXEL(v1, 1) FIN_PIXEL(v2, 2)
    FIN_PIXEL(v3, 3) FIN_PIXEL(v4, 4) FIN_PIXEL(v5, 5)
    FIN_PIXEL(v6, 6) FIN_PIXEL(v7, 7) FIN_PIXEL(v8, 8)
}

extern "C" void kernel_launch(void* const* d_in, const int* in_sizes, int n_in,
                              void* d_out, int out_size, void* d_ws, size_t ws_size,
                              hipStream_t stream) {
    // dict order: x, w_pre, b_pre, w_loop, b_loop, w_shared, b_shared
    const float* x  = (const float*)d_in[0];
    const float* wp = (const float*)d_in[1];
    const float* bp = (const float*)d_in[2];
    const float* wl = (const float*)d_in[3];
    const float* bl = (const float*)d_in[4];
    const float* ws = (const float*)d_in[5];
    const float* bs = (const float*)d_in[6];
    float* out = (float*)d_out;
    Ctl*   ctl = (Ctl*)d_ws;

    k_init<<<1, 64, 0, stream>>>(ctl);
    k_persist<<<NBLK, TPB, 0, stream>>>(x, wp, bp, wl, bl, ws, bs, out, ctl);
}

// Round 7
// 478.988 us; speedup vs baseline: 4.9684x; 1.0746x over previous
//
#include <hip/hip_runtime.h>
#include <math.h>

// Problem constants: B=8, CIN=3, COUT=16, H=W=384
#define BQ   8
#define CIN  3
#define COUT 16
#define HW   (384 * 384)            // 147456
#define NPIX (BQ * HW)              // 1,179,648 pixels
#define NELT 18874368.0f            // NPIX * COUT
#define MAX_ITERS 16

#define TPB       256
#define BPC       3                 // 3 blocks/CU => 12 waves/CU, ~170 VGPR budget
#define NBLK      (BPC * 256)       // 768 blocks, co-resident by construction
#define NTHREADS  (NBLK * TPB)      // 196,608
#define PPT       6                 // 196,608 * 6 == NPIX exactly; 96 state floats/thread
                                    // SINGLE-pixel steps: ~96+16+25 live << 170 (R2's
                                    // spill came from pair-processing's +32 temps)

#define NLEAF        64
#define BLK_PER_LEAF (NBLK / NLEAF) // 12

typedef float vfloat16 __attribute__((ext_vector_type(16)));

struct __align__(64) PadCnt { int cnt; int pad[15]; };  // one cache line each

struct Ctl {
    PadCnt leaf[NLEAF];                 // barrier leaf counters (12-way fan-in)
    PadCnt root;                        // barrier root counter (64-way fan-in)
    PadCnt sense;                       // barrier sense (read-only spin target)
    float  partials[2][NBLK];           // ping-pong per-block |v| partial sums
};

__global__ void k_init(Ctl* c) {
    int t = threadIdx.x;
    if (t < NLEAF) c->leaf[t].cnt = 0;
    if (t == 0) { c->root.cnt = 0; c->sense.cnt = 0; }
}

// tanh(x) = 1 - 2/(exp(2x)+1): v_exp_f32 + v_rcp_f32, ~6 instrs, ~1e-7 abs err.
__device__ __forceinline__ float tanh_fast(float x) {
    float e = __expf(2.0f * x);
    return fmaf(-2.0f, __builtin_amdgcn_rcpf(e + 1.0f), 1.0f);
}

// block = 256 threads = 4 waves; full block sum returned on tid 0
__device__ __forceinline__ float block_reduce_add(float v) {
    #pragma unroll
    for (int off = 32; off > 0; off >>= 1)
        v += __shfl_down(v, off, 64);
    __shared__ float red[TPB / 64];
    int lane = threadIdx.x & 63;
    int wid  = threadIdx.x >> 6;
    if (lane == 0) red[wid] = v;
    __syncthreads();
    float r = 0.f;
    if (threadIdx.x == 0) {
        #pragma unroll
        for (int i = 0; i < TPB / 64; ++i) r += red[i];
    }
    return r;
}

// Two-level sense-reversing grid barrier (R0's proven-fastest variant):
// leaf fan-in 12, root fan-in 64, acq_rel arrivals, acquire-load spin.
__device__ __forceinline__ void grid_barrier(Ctl* c, int* sense_sh) {
    __syncthreads();
    if (threadIdx.x == 0) {
        int next = *sense_sh ^ 1;
        int lf = blockIdx.x & (NLEAF - 1);
        int p = __hip_atomic_fetch_add(&c->leaf[lf].cnt, 1, __ATOMIC_ACQ_REL,
                                       __HIP_MEMORY_SCOPE_AGENT);
        if (p == BLK_PER_LEAF - 1) {
            __hip_atomic_store(&c->leaf[lf].cnt, 0, __ATOMIC_RELAXED,
                               __HIP_MEMORY_SCOPE_AGENT);
            int q = __hip_atomic_fetch_add(&c->root.cnt, 1, __ATOMIC_ACQ_REL,
                                           __HIP_MEMORY_SCOPE_AGENT);
            if (q == NLEAF - 1) {
                __hip_atomic_store(&c->root.cnt, 0, __ATOMIC_RELAXED,
                                   __HIP_MEMORY_SCOPE_AGENT);
                __hip_atomic_store(&c->sense.cnt, next, __ATOMIC_RELEASE,
                                   __HIP_MEMORY_SCOPE_AGENT);
            }
        }
        while (__hip_atomic_load(&c->sense.cnt, __ATOMIC_ACQUIRE,
                                 __HIP_MEMORY_SCOPE_AGENT) != next)
            __builtin_amdgcn_s_sleep(4);
        *sense_sh = next;
    }
    __syncthreads();
}

// Deterministic grid sum: wave 0 sums all NBLK partials in a fixed order
// (identical in every block -> bitwise-identical -> uniform decision).
__device__ __forceinline__ float grid_sum(const float* part, float* bc) {
    int lane = threadIdx.x & 63, wid = threadIdx.x >> 6;
    if (wid == 0) {
        float s = 0.f;
        #pragma unroll
        for (int i = 0; i < NBLK / 64; ++i)
            s += __hip_atomic_load(&part[i * 64 + lane], __ATOMIC_RELAXED,
                                   __HIP_MEMORY_SCOPE_AGENT);
        #pragma unroll
        for (int off = 32; off > 0; off >>= 1)
            s += __shfl_down(s, off, 64);
        if (lane == 0) *bc = s;
    }
    __syncthreads();
    return *bc;
}

// ---- per-pixel macros over NAMED ext-vectors (no arrays -> guaranteed SROA) ----

#define PRE_PIXEL(vk, kk)                                                \
    { int p = tid + (kk) * NTHREADS; int b = p / HW; int hw = p - b * HW;\
      const float* xb = x + (size_t)b * (CIN * HW) + hw;                 \
      float x0 = xb[0], x1 = xb[HW], x2 = xb[2 * HW];                    \
      _Pragma("unroll")                                                  \
      for (int o = 0; o < COUT; ++o) {                                   \
          float a = bp[o];                                               \
          a = fmaf(wp[o * CIN + 0], x0, a);                              \
          a = fmaf(wp[o * CIN + 1], x1, a);                              \
          a = fmaf(wp[o * CIN + 2], x2, a);                              \
          vk[o] = a; s += fabsf(a);                                      \
      } }

#define STEP_PIXEL(vk)                                                   \
    { float tt[COUT];                                                    \
      _Pragma("unroll")                                                  \
      for (int o = 0; o < COUT; ++o) {                                   \
          float a = bs[o];                                               \
          _Pragma("unroll")                                              \
          for (int c = 0; c < COUT; ++c)                                 \
              a = fmaf(ws[o * COUT + c], vk[c], a);                      \
          tt[o] = tanh_fast(a);                                          \
      }                                                                  \
      _Pragma("unroll")                                                  \
      for (int o = 0; o < COUT; ++o) {                                   \
          float a = bl[o];                                               \
          _Pragma("unroll")                                              \
          for (int c = 0; c < COUT; ++c)                                 \
              a = fmaf(wl[o * COUT + c], tt[c], a);                      \
          a *= 10.f;                                                     \
          vk[o] = a; s += fabsf(a);                                      \
      } }

#define FIN_PIXEL(vk, kk)                                                \
    { int p = tid + (kk) * NTHREADS; int b = p / HW; int hw = p - b * HW;\
      float* ob = out + (size_t)b * (COUT * HW) + hw;                    \
      _Pragma("unroll")                                                  \
      for (int o = 0; o < COUT; ++o) {                                   \
          float a = bs[o];                                               \
          _Pragma("unroll")                                              \
          for (int c = 0; c < COUT; ++c)                                 \
              a = fmaf(ws[o * COUT + c], vk[c], a);                      \
          ob[(size_t)o * HW] = a;                                        \
      } }

__global__ __launch_bounds__(TPB, BPC) void k_persist(
        const float* __restrict__ x,
        const float* __restrict__ wp, const float* __restrict__ bp,
        const float* __restrict__ wl, const float* __restrict__ bl,
        const float* __restrict__ ws, const float* __restrict__ bs,
        float* __restrict__ out, Ctl* __restrict__ ctl) {
    __shared__ int sense_sh;
    __shared__ float bcast;
    const int t = threadIdx.x;
    if (t == 0) sense_sh = 0;
    __syncthreads();

    const int tid = blockIdx.x * TPB + t;

    // State: 6 named 16-wide vectors = 96 registers. No runtime indexing.
    vfloat16 v0, v1, v2, v3, v4, v5;

    // ---- pre conv + |v| partial
    float s = 0.f;
    PRE_PIXEL(v0, 0) PRE_PIXEL(v1, 1) PRE_PIXEL(v2, 2)
    PRE_PIXEL(v3, 3) PRE_PIXEL(v4, 4) PRE_PIXEL(v5, 5)
    {
        float r = block_reduce_add(s);
        if (t == 0)
            __hip_atomic_store(&ctl->partials[0][blockIdx.x], r,
                               __ATOMIC_RELAXED, __HIP_MEMORY_SCOPE_AGENT);
    }
    grid_barrier(ctl, &sense_sh);

    // ---- while (mean|v| < 3): v = 10*(wl @ tanh(ws @ v + bs) + bl)
    int it = 0;
    while (it < MAX_ITERS) {
        float total = grid_sum(ctl->partials[it & 1], &bcast);
        if (total >= 3.0f * NELT) break;      // uniform across all blocks

        s = 0.f;
        STEP_PIXEL(v0) STEP_PIXEL(v1) STEP_PIXEL(v2)
        STEP_PIXEL(v3) STEP_PIXEL(v4) STEP_PIXEL(v5)
        ++it;
        float r = block_reduce_add(s);
        if (t == 0)
            __hip_atomic_store(&ctl->partials[it & 1][blockIdx.x], r,
                               __ATOMIC_RELAXED, __HIP_MEMORY_SCOPE_AGENT);
        grid_barrier(ctl, &sense_sh);
    }

    // ---- final conv
    FIN_PIXEL(v0, 0) FIN_PIXEL(v1, 1) FIN_PIXEL(v2, 2)
    FIN_PIXEL(v3, 3) FIN_PIXEL(v4, 4) FIN_PIXEL(v5, 5)
}

extern "C" void kernel_launch(void* const* d_in, const int* in_sizes, int n_in,
                              void* d_out, int out_size, void* d_ws, size_t ws_size,
                              hipStream_t stream) {
    // dict order: x, w_pre, b_pre, w_loop, b_loop, w_shared, b_shared
    const float* x  = (const float*)d_in[0];
    const float* wp = (const float*)d_in[1];
    const float* bp = (const float*)d_in[2];
    const float* wl = (const float*)d_in[3];
    const float* bl = (const float*)d_in[4];
    const float* ws = (const float*)d_in[5];
    const float* bs = (const float*)d_in[6];
    float* out = (float*)d_out;
    Ctl*   ctl = (Ctl*)d_ws;

    k_init<<<1, 64, 0, stream>>>(ctl);
    k_persist<<<NBLK, TPB, 0, stream>>>(x, wp, bp, wl, bl, ws, bs, out, ctl);
}

// Round 8
// 448.740 us; speedup vs baseline: 5.3033x; 1.0674x over previous
//
#include <hip/hip_runtime.h>
#include <math.h>

// Problem constants: B=8, CIN=3, COUT=16, H=W=384
#define BQ   8
#define CIN  3
#define COUT 16
#define HW   (384 * 384)            // 147456
#define NPIX (BQ * HW)              // 1,179,648 pixels
#define NELT 18874368.0f            // NPIX * COUT
#define MAX_ITERS 16

#define TPB       256
#define BPC       2                 // 2 blocks/CU: the PROVEN zero-spill budget (256 reg/wave)
#define NBLK      (BPC * 256)       // 512 blocks, co-resident by construction
#define NTHREADS  (NBLK * TPB)      // 131,072
#define PPT       9                 // 131,072 * 9 == NPIX exactly; 144 state floats/thread

#define NLEAF        64
#define BLK_PER_LEAF (NBLK / NLEAF) // 8

#define SCOPE_AGENT __HIP_MEMORY_SCOPE_AGENT

typedef float vfloat16 __attribute__((ext_vector_type(16)));
typedef float v2f      __attribute__((ext_vector_type(2)));

// One cache line per node: arrival counter + float accumulator.
struct __align__(64) Node { int cnt; float acc; int pad[14]; };

struct Ctl {
    Node leaf[NLEAF];   // leaf fan-in 8: counts + partial-sum accumulation
    Node root;          // root fan-in 64
    Node sense;         // .cnt = monotonically increasing (round<<1 | stop)
};

__global__ void k_init(Ctl* c) {
    int t = threadIdx.x;
    if (t < NLEAF) { c->leaf[t].cnt = 0; c->leaf[t].acc = 0.f; }
    if (t == 0) {
        c->root.cnt = 0; c->root.acc = 0.f;
        c->sense.cnt = 0; c->sense.acc = 0.f;
    }
}

// tanh(x) = 1 - 2/(exp(2x)+1): v_exp_f32 + v_rcp_f32, ~6 instrs, ~1e-7 abs err.
__device__ __forceinline__ float tanh_fast(float x) {
    float e = __expf(2.0f * x);
    return fmaf(-2.0f, __builtin_amdgcn_rcpf(e + 1.0f), 1.0f);
}

// Completion fence for agent-scope atomics (they execute at the LLC):
// draining vmcnt orders RMW pairs without any cache maintenance.
__device__ __forceinline__ void vm_drain() {
    asm volatile("s_waitcnt vmcnt(0)" ::: "memory");
}

// block = 256 threads = 4 waves; full block sum returned on tid 0
__device__ __forceinline__ float block_reduce_add(float v) {
    #pragma unroll
    for (int off = 32; off > 0; off >>= 1)
        v += __shfl_down(v, off, 64);
    __shared__ float red[TPB / 64];
    int lane = threadIdx.x & 63;
    int wid  = threadIdx.x >> 6;
    if (lane == 0) red[wid] = v;
    __syncthreads();
    float r = 0.f;
    if (threadIdx.x == 0) {
        #pragma unroll
        for (int i = 0; i < TPB / 64; ++i) r += red[i];
    }
    return r;
}

// Fused reduction + barrier + CENTRAL uniform decision.
// Arrival path (R6-proven): relaxed float-atomic accumulate up a leaf/root
// tree, vm_drain() ordering each acc->cnt pair. The root-last block alone
// evaluates the stop condition and release-publishes (round<<1 | stop) in ONE
// word. Spin is R0's proven acquire-load spin. This removes the NBLK^2
// atomic-load scatter of the old grid_sum (every block reading every partial)
// -> NBLK single-line reads.
__device__ __forceinline__ int arrive_and_decide(Ctl* c, float v, int round,
                                                 int* stop_sh) {
    float r = block_reduce_add(v);
    if (threadIdx.x == 0) {
        int lf = blockIdx.x & (NLEAF - 1);
        __hip_atomic_fetch_add(&c->leaf[lf].acc, r, __ATOMIC_RELAXED, SCOPE_AGENT);
        vm_drain();                                   // acc landed before cnt
        int p = __hip_atomic_fetch_add(&c->leaf[lf].cnt, 1, __ATOMIC_RELAXED,
                                       SCOPE_AGENT);
        if (p == BLK_PER_LEAF - 1) {
            float sl = __hip_atomic_exchange(&c->leaf[lf].acc, 0.0f,
                                             __ATOMIC_RELAXED, SCOPE_AGENT);
            __hip_atomic_exchange(&c->leaf[lf].cnt, 0, __ATOMIC_RELAXED,
                                  SCOPE_AGENT);
            vm_drain();                               // resets done before root
            __hip_atomic_fetch_add(&c->root.acc, sl, __ATOMIC_RELAXED,
                                   SCOPE_AGENT);
            vm_drain();
            int q = __hip_atomic_fetch_add(&c->root.cnt, 1, __ATOMIC_RELAXED,
                                           SCOPE_AGENT);
            if (q == NLEAF - 1) {
                float total = __hip_atomic_exchange(&c->root.acc, 0.0f,
                                                    __ATOMIC_RELAXED, SCOPE_AGENT);
                __hip_atomic_exchange(&c->root.cnt, 0, __ATOMIC_RELAXED,
                                      SCOPE_AGENT);
                vm_drain();                           // resets done before publish
                int stop = (total >= 3.0f * NELT) ? 1 : 0;
                __hip_atomic_store(&c->sense.cnt, (round << 1) | stop,
                                   __ATOMIC_RELEASE, SCOPE_AGENT);
            }
        }
        // acquire-load spin (R0-proven fastest; nothing dirty in L2 to flush)
        int s;
        for (;;) {
            s = __hip_atomic_load(&c->sense.cnt, __ATOMIC_ACQUIRE, SCOPE_AGENT);
            if ((s >> 1) >= round) break;
            __builtin_amdgcn_s_sleep(2);
        }
        *stop_sh = s & 1;
    }
    __syncthreads();
    return *stop_sh;
}

// ---- per-pixel macros over NAMED ext-vectors (no arrays -> guaranteed SROA) ----
// GEMVs packed over channel PAIRS: <2 x float> elementwise_fma -> v_pk_fma_f32
// (2 FMAs/instr); weight pairs come in as uniform 64-bit scalar loads.
// Fallback if pk doesn't form: two scalar FMAs (no loss).

#define PRE_PIXEL(vk, kk)                                                \
    { int p = tid + (kk) * NTHREADS; int b = p / HW; int hw = p - b * HW;\
      const float* xb = x + (size_t)b * (CIN * HW) + hw;                 \
      float x0 = xb[0], x1 = xb[HW], x2 = xb[2 * HW];                    \
      _Pragma("unroll")                                                  \
      for (int o = 0; o < COUT; ++o) {                                   \
          float a = bp[o];                                               \
          a = fmaf(wp[o * CIN + 0], x0, a);                              \
          a = fmaf(wp[o * CIN + 1], x1, a);                              \
          a = fmaf(wp[o * CIN + 2], x2, a);                              \
          vk[o] = a; s += fabsf(a);                                      \
      } }

#define STEP_PIXEL(vk)                                                   \
    { float tt[COUT];                                                    \
      _Pragma("unroll")                                                  \
      for (int o = 0; o < COUT; ++o) {                                   \
          v2f acc2 = {bs[o], 0.0f};                                      \
          _Pragma("unroll")                                              \
          for (int c2 = 0; c2 < COUT / 2; ++c2) {                        \
              v2f vv = {vk[2 * c2], vk[2 * c2 + 1]};                     \
              v2f ww = *(const v2f*)(ws + o * COUT + 2 * c2);            \
              acc2 = __builtin_elementwise_fma(ww, vv, acc2);            \
          }                                                              \
          tt[o] = tanh_fast(acc2.x + acc2.y);                            \
      }                                                                  \
      _Pragma("unroll")                                                  \
      for (int o = 0; o < COUT; ++o) {                                   \
          v2f acc2 = {bl[o], 0.0f};                                      \
          _Pragma("unroll")                                              \
          for (int c2 = 0; c2 < COUT / 2; ++c2) {                        \
              v2f vv = {tt[2 * c2], tt[2 * c2 + 1]};                     \
              v2f ww = *(const v2f*)(wl + o * COUT + 2 * c2);            \
              acc2 = __builtin_elementwise_fma(ww, vv, acc2);            \
          }                                                              \
          float a = (acc2.x + acc2.y) * 10.f;                            \
          vk[o] = a; s += fabsf(a);                                      \
      } }

#define FIN_PIXEL(vk, kk)                                                \
    { int p = tid + (kk) * NTHREADS; int b = p / HW; int hw = p - b * HW;\
      float* ob = out + (size_t)b * (COUT * HW) + hw;                    \
      _Pragma("unroll")                                                  \
      for (int o = 0; o < COUT; ++o) {                                   \
          v2f acc2 = {bs[o], 0.0f};                                      \
          _Pragma("unroll")                                              \
          for (int c2 = 0; c2 < COUT / 2; ++c2) {                        \
              v2f vv = {vk[2 * c2], vk[2 * c2 + 1]};                     \
              v2f ww = *(const v2f*)(ws + o * COUT + 2 * c2);            \
              acc2 = __builtin_elementwise_fma(ww, vv, acc2);            \
          }                                                              \
          ob[(size_t)o * HW] = acc2.x + acc2.y;                          \
      } }

__global__ __launch_bounds__(TPB, BPC) void k_persist(
        const float* __restrict__ x,
        const float* __restrict__ wp, const float* __restrict__ bp,
        const float* __restrict__ wl, const float* __restrict__ bl,
        const float* __restrict__ ws, const float* __restrict__ bs,
        float* __restrict__ out, Ctl* __restrict__ ctl) {
    __shared__ int stop_sh;
    const int t = threadIdx.x;
    const int tid = blockIdx.x * TPB + t;

    // State: 9 named 16-wide vectors = 144 registers. No runtime indexing.
    // Proven zero-spill at 2 blocks/CU (R0/R6: FETCH ~13 MB, WRITE ~84 MB).
    vfloat16 v0, v1, v2, v3, v4, v5, v6, v7, v8;

    // ---- pre conv + |v| partial
    float s = 0.f;
    PRE_PIXEL(v0, 0) PRE_PIXEL(v1, 1) PRE_PIXEL(v2, 2)
    PRE_PIXEL(v3, 3) PRE_PIXEL(v4, 4) PRE_PIXEL(v5, 5)
    PRE_PIXEL(v6, 6) PRE_PIXEL(v7, 7) PRE_PIXEL(v8, 8)

    int round = 1;
    int stop = arrive_and_decide(ctl, s, round, &stop_sh);

    // ---- while (mean|v| < 3): v = 10*(wl @ tanh(ws @ v + bs) + bl)
    int it = 0;
    while (!stop && it < MAX_ITERS) {
        s = 0.f;
        STEP_PIXEL(v0) STEP_PIXEL(v1) STEP_PIXEL(v2)
        STEP_PIXEL(v3) STEP_PIXEL(v4) STEP_PIXEL(v5)
        STEP_PIXEL(v6) STEP_PIXEL(v7) STEP_PIXEL(v8)
        ++it; ++round;
        stop = arrive_and_decide(ctl, s, round, &stop_sh);
    }

    // ---- final conv
    FIN_PIXEL(v0, 0) FIN_PIXEL(v1, 1) FIN_PIXEL(v2, 2)
    FIN_PIXEL(v3, 3) FIN_PIXEL(v4, 4) FIN_PIXEL(v5, 5)
    FIN_PIXEL(v6, 6) FIN_PIXEL(v7, 7) FIN_PIXEL(v8, 8)
}

extern "C" void kernel_launch(void* const* d_in, const int* in_sizes, int n_in,
                              void* d_out, int out_size, void* d_ws, size_t ws_size,
                              hipStream_t stream) {
    // dict order: x, w_pre, b_pre, w_loop, b_loop, w_shared, b_shared
    const float* x  = (const float*)d_in[0];
    const float* wp = (const float*)d_in[1];
    const float* bp = (const float*)d_in[2];
    const float* wl = (const float*)d_in[3];
    const float* bl = (const float*)d_in[4];
    const float* ws = (const float*)d_in[5];
    const float* bs = (const float*)d_in[6];
    float* out = (float*)d_out;
    Ctl*   ctl = (Ctl*)d_ws;

    k_init<<<1, 64, 0, stream>>>(ctl);
    k_persist<<<NBLK, TPB, 0, stream>>>(x, wp, bp, wl, bl, ws, bs, out, ctl);
}

// Round 9
// 418.355 us; speedup vs baseline: 5.6885x; 1.0726x over previous
//
#include <hip/hip_runtime.h>
#include <math.h>

// Problem constants: B=8, CIN=3, COUT=16, H=W=384
#define BQ   8
#define CIN  3
#define COUT 16
#define HW   (384 * 384)            // 147456
#define NPIX (BQ * HW)              // 1,179,648 pixels
#define NELT 18874368.0f            // NPIX * COUT
#define MAX_ITERS 16

#define TPB       256
#define BPC       2                 // 2 blocks/CU: the PROVEN zero-spill budget (256 reg/wave)
#define NBLK      (BPC * 256)       // 512 blocks, co-resident by construction
#define NTHREADS  (NBLK * TPB)      // 131,072
#define PPT       9                 // 131,072 * 9 == NPIX exactly; 144 state floats/thread

#define SCOPE_AGENT __HIP_MEMORY_SCOPE_AGENT

typedef float vfloat16 __attribute__((ext_vector_type(16)));

// Flat barrier state: ONE cache line, zero-initialized by hipMemsetAsync
// (no k_init kernel launch). sense is monotonic (round<<1 | stop), so 0 is a
// valid "before round 1" value.
struct __align__(64) Ctl { int cnt; float acc; int sense; int pad[13]; };

// tanh(x) = 1 - 2/(exp(2x)+1): v_exp_f32 + v_rcp_f32, ~6 instrs, ~1e-7 abs err.
__device__ __forceinline__ float tanh_fast(float x) {
    float e = __expf(2.0f * x);
    return fmaf(-2.0f, __builtin_amdgcn_rcpf(e + 1.0f), 1.0f);
}

// Completion fence for agent-scope atomics (they execute at the LLC):
// draining vmcnt orders RMW pairs without any cache maintenance.
__device__ __forceinline__ void vm_drain() {
    asm volatile("s_waitcnt vmcnt(0)" ::: "memory");
}

// block = 256 threads = 4 waves; full block sum returned on tid 0
__device__ __forceinline__ float block_reduce_add(float v) {
    #pragma unroll
    for (int off = 32; off > 0; off >>= 1)
        v += __shfl_down(v, off, 64);
    __shared__ float red[TPB / 64];
    int lane = threadIdx.x & 63;
    int wid  = threadIdx.x >> 6;
    if (lane == 0) red[wid] = v;
    __syncthreads();
    float r = 0.f;
    if (threadIdx.x == 0) {
        #pragma unroll
        for (int i = 0; i < TPB / 64; ++i) r += red[i];
    }
    return r;
}

// FLAT fused reduction + barrier + central uniform decision.
// Same-line LLC atomics pipeline; critical path = one RMW round-trip + publish
// (the old leaf/root tree paid 2+ serial LLC round-trips per round).
// Ordering: each block drains its acc-add before its cnt-add, so the block
// observing cnt==NBLK-1 knows ALL acc-adds have landed. Resets drain before
// the RELEASE publish; spinners ACQUIRE-load the monotonic sense word.
__device__ __forceinline__ int arrive_and_decide(Ctl* c, float v, int round,
                                                 int* stop_sh) {
    float r = block_reduce_add(v);
    if (threadIdx.x == 0) {
        __hip_atomic_fetch_add(&c->acc, r, __ATOMIC_RELAXED, SCOPE_AGENT);
        vm_drain();                                   // acc landed before cnt
        int p = __hip_atomic_fetch_add(&c->cnt, 1, __ATOMIC_RELAXED,
                                       SCOPE_AGENT);
        if (p == NBLK - 1) {
            float total = __hip_atomic_exchange(&c->acc, 0.0f,
                                                __ATOMIC_RELAXED, SCOPE_AGENT);
            __hip_atomic_exchange(&c->cnt, 0, __ATOMIC_RELAXED, SCOPE_AGENT);
            vm_drain();                               // resets done before publish
            int stop = (total >= 3.0f * NELT) ? 1 : 0;
            __hip_atomic_store(&c->sense, (round << 1) | stop,
                               __ATOMIC_RELEASE, SCOPE_AGENT);
        }
        int s;
        for (;;) {
            s = __hip_atomic_load(&c->sense, __ATOMIC_ACQUIRE, SCOPE_AGENT);
            if ((s >> 1) >= round) break;
            __builtin_amdgcn_s_sleep(2);
        }
        *stop_sh = s & 1;
    }
    __syncthreads();
    return *stop_sh;
}

// ---- per-pixel macros over NAMED ext-vectors (no arrays -> guaranteed SROA).
// R0's exact scalar step: proven cleanest counters (FETCH 12.5 MB, WRITE 83 MB,
// zero spill at 2 blocks/CU).

#define PRE_PIXEL(vk, kk)                                                \
    { int p = tid + (kk) * NTHREADS; int b = p / HW; int hw = p - b * HW;\
      const float* xb = x + (size_t)b * (CIN * HW) + hw;                 \
      float x0 = xb[0], x1 = xb[HW], x2 = xb[2 * HW];                    \
      _Pragma("unroll")                                                  \
      for (int o = 0; o < COUT; ++o) {                                   \
          float a = bp[o];                                               \
          a = fmaf(wp[o * CIN + 0], x0, a);                              \
          a = fmaf(wp[o * CIN + 1], x1, a);                              \
          a = fmaf(wp[o * CIN + 2], x2, a);                              \
          vk[o] = a; s += fabsf(a);                                      \
      } }

#define STEP_PIXEL(vk)                                                   \
    { float tt[COUT];                                                    \
      _Pragma("unroll")                                                  \
      for (int o = 0; o < COUT; ++o) {                                   \
          float a = bs[o];                                               \
          _Pragma("unroll")                                              \
          for (int c = 0; c < COUT; ++c)                                 \
              a = fmaf(ws[o * COUT + c], vk[c], a);                      \
          tt[o] = tanh_fast(a);                                          \
      }                                                                  \
      _Pragma("unroll")                                                  \
      for (int o = 0; o < COUT; ++o) {                                   \
          float a = bl[o];                                               \
          _Pragma("unroll")                                              \
          for (int c = 0; c < COUT; ++c)                                 \
              a = fmaf(wl[o * COUT + c], tt[c], a);                      \
          a *= 10.f;                                                     \
          vk[o] = a; s += fabsf(a);                                      \
      } }

#define FIN_PIXEL(vk, kk)                                                \
    { int p = tid + (kk) * NTHREADS; int b = p / HW; int hw = p - b * HW;\
      float* ob = out + (size_t)b * (COUT * HW) + hw;                    \
      _Pragma("unroll")                                                  \
      for (int o = 0; o < COUT; ++o) {                                   \
          float a = bs[o];                                               \
          _Pragma("unroll")                                              \
          for (int c = 0; c < COUT; ++c)                                 \
              a = fmaf(ws[o * COUT + c], vk[c], a);                      \
          ob[(size_t)o * HW] = a;                                        \
      } }

__global__ __launch_bounds__(TPB, BPC) void k_persist(
        const float* __restrict__ x,
        const float* __restrict__ wp, const float* __restrict__ bp,
        const float* __restrict__ wl, const float* __restrict__ bl,
        const float* __restrict__ ws, const float* __restrict__ bs,
        float* __restrict__ out, Ctl* __restrict__ ctl) {
    __shared__ int stop_sh;
    const int t = threadIdx.x;
    const int tid = blockIdx.x * TPB + t;

    // State: 9 named 16-wide vectors = 144 registers. No runtime indexing.
    vfloat16 v0, v1, v2, v3, v4, v5, v6, v7, v8;

    // ---- pre conv + |v| partial
    float s = 0.f;
    PRE_PIXEL(v0, 0) PRE_PIXEL(v1, 1) PRE_PIXEL(v2, 2)
    PRE_PIXEL(v3, 3) PRE_PIXEL(v4, 4) PRE_PIXEL(v5, 5)
    PRE_PIXEL(v6, 6) PRE_PIXEL(v7, 7) PRE_PIXEL(v8, 8)

    int round = 1;
    int stop = arrive_and_decide(ctl, s, round, &stop_sh);

    // ---- while (mean|v| < 3): v = 10*(wl @ tanh(ws @ v + bs) + bl)
    int it = 0;
    while (!stop && it < MAX_ITERS) {
        s = 0.f;
        STEP_PIXEL(v0) STEP_PIXEL(v1) STEP_PIXEL(v2)
        STEP_PIXEL(v3) STEP_PIXEL(v4) STEP_PIXEL(v5)
        STEP_PIXEL(v6) STEP_PIXEL(v7) STEP_PIXEL(v8)
        ++it; ++round;
        stop = arrive_and_decide(ctl, s, round, &stop_sh);
    }

    // ---- final conv
    FIN_PIXEL(v0, 0) FIN_PIXEL(v1, 1) FIN_PIXEL(v2, 2)
    FIN_PIXEL(v3, 3) FIN_PIXEL(v4, 4) FIN_PIXEL(v5, 5)
    FIN_PIXEL(v6, 6) FIN_PIXEL(v7, 7) FIN_PIXEL(v8, 8)
}

extern "C" void kernel_launch(void* const* d_in, const int* in_sizes, int n_in,
                              void* d_out, int out_size, void* d_ws, size_t ws_size,
                              hipStream_t stream) {
    // dict order: x, w_pre, b_pre, w_loop, b_loop, w_shared, b_shared
    const float* x  = (const float*)d_in[0];
    const float* wp = (const float*)d_in[1];
    const float* bp = (const float*)d_in[2];
    const float* wl = (const float*)d_in[3];
    const float* bl = (const float*)d_in[4];
    const float* ws = (const float*)d_in[5];
    const float* bs = (const float*)d_in[6];
    float* out = (float*)d_out;
    Ctl*   ctl = (Ctl*)d_ws;

    // Zero the 64-byte barrier line with a DMA packet instead of a kernel
    // launch (graph-capture-safe; saves one dispatch per replay).
    hipMemsetAsync(ctl, 0, sizeof(Ctl), stream);
    k_persist<<<NBLK, TPB, 0, stream>>>(x, wp, bp, wl, bl, ws, bs, out, ctl);
}